// Round 7
// baseline (162.037 us; speedup 1.0000x reference)
//
#include <hip/hip_runtime.h>
#include <stdint.h>

typedef _Float16 f16;
typedef _Float16 f16x8 __attribute__((ext_vector_type(8)));
typedef _Float16 f16x4 __attribute__((ext_vector_type(4)));
typedef float f32x4 __attribute__((ext_vector_type(4)));

#define D_DIM 4096
#define H_DIM 256
#define E_DIM 64
#define BM 128
#define BK 64
#define KSPLIT 4
#define NKT2 16                 // K-steps per slice: 1024/64
#define HP_SLICE (8192 * 256)   // f32 elems per hpart slice
#define REP 2                   // instrumentation: internal repeat (acc summed, scaled by 1/REP)

// ---- merged pack: w1 [4096][256] -> w1s fragment order; w2 [256][64] -> w2s ----
__global__ void pack_kernel(const float* __restrict__ w1, f16* __restrict__ w1s,
                            const float* __restrict__ w2, f16* __restrict__ w2s) {
  const int b = blockIdx.x;
  const int t = threadIdx.x;
  if (b < 512) {
    const int u = b * 256 + t;
    const int lane = u & 63;
    const int kk = (u >> 6) & 1;
    const int c16 = (u >> 7) & 15;
    const int kt = u >> 11;
    const int g = lane >> 4, r = lane & 15;
    const int k0 = kt * 64 + kk * 32 + g * 8;
    const int col = c16 * 16 + r;
    f16x8 o;
#pragma unroll
    for (int j = 0; j < 8; ++j) o[j] = (f16)w1[(size_t)(k0 + j) * H_DIM + col];
    *(f16x8*)(w1s + (size_t)u * 8) = o;
  } else {
    const int u = (b - 512) * 256 + t;
    const int lane = u & 63;
    const int ks = (u >> 6) & 7;
    const int cg = u >> 9;
    const int g = lane >> 4, r = lane & 15;
    const int k0 = ks * 32 + g * 8;
    const int col = cg * 16 + r;
    f16x8 o;
#pragma unroll
    for (int j = 0; j < 8; ++j) o[j] = (f16)w2[(size_t)(k0 + j) * E_DIM + col];
    *(f16x8*)(w2s + (size_t)u * 8) = o;
  }
}

// ---- GEMM1 split-K, BM=128, circular K, REP internal sweeps (measurement round) ----
__launch_bounds__(512, 2)
__global__ void gemm1_splitk_kernel(const float* __restrict__ x,
                                    const f16* __restrict__ w1s,
                                    float* __restrict__ hpart) {
  __shared__ __align__(16) f16 buf0[BM * BK];  // 16 KB
  __shared__ __align__(16) f16 buf1[BM * BK];  // 16 KB

  const int t = threadIdx.x;
  const int lane = t & 63;
  const int wn = t >> 6;
  const int wm = wn >> 2;       // 0..1  (row half: 64 rows)
  const int wc = wn & 3;        // 0..3  (col group: 64 cols)
  const int g = lane >> 4, r = lane & 15;
  const int bid = blockIdx.x;
  const int ks = bid & 3;
  const int brow = (bid >> 2) * BM;
  const int kph = (bid * 5) & 15;   // per-block K phase

#define KT(s) ((kph + (s)) & 15)

  const float* xb = x + (size_t)(brow + (t >> 4)) * D_DIM + ks * 1024 + ((t & 15) << 2);
  const int stw_swz = (((t & 15) << 2) ^ (((t >> 4) & 7) << 3));
  const int stw_row0 = (t >> 4);

  const f16* bptr = w1s + (size_t)ks * (16 * 16384) + (size_t)(wc * 8) * 512 + lane * 8;

  f32x4 acc[4][4];
#pragma unroll
  for (int mf = 0; mf < 4; ++mf)
#pragma unroll
    for (int nf = 0; nf < 4; ++nf) acc[mf][nf] = (f32x4){0.f, 0.f, 0.f, 0.f};

  f16x8 BE[8], BO[8];          // B frags [nf*2+kk]
  float4 xA[4], xB[4], xP[4];  // staged x (4 float4 each)

#define LDX(kt, xr)                                                     \
  {                                                                     \
    _Pragma("unroll") for (int i = 0; i < 4; ++i)                       \
      (xr)[i] = *(const float4*)(xb + (size_t)i * (32 * D_DIM) + (kt) * 64); \
  }
#define LDB(kt, B)                                                      \
  {                                                                     \
    const f16* p_ = bptr + (size_t)(kt) * 16384;                        \
    _Pragma("unroll") for (int q = 0; q < 8; ++q)                       \
      (B)[q] = *(const f16x8*)(p_ + q * 512);                           \
  }
#define STW(dst, xr)                                                    \
  {                                                                     \
    _Pragma("unroll") for (int i = 0; i < 4; ++i) {                     \
      f16x4 hv_;                                                        \
      hv_[0] = (f16)(xr)[i].x; hv_[1] = (f16)(xr)[i].y;                 \
      hv_[2] = (f16)(xr)[i].z; hv_[3] = (f16)(xr)[i].w;                 \
      *(f16x4*)((dst) + (i * 32 + stw_row0) * 64 + stw_swz) = hv_;      \
    }                                                                   \
  }
#define COMP(buf, B)                                                           \
  {                                                                            \
    _Pragma("unroll") for (int kk = 0; kk < 2; ++kk) {                         \
      const int kb_ = (kk * 32 + g * 8) ^ ((r & 7) << 3);                      \
      _Pragma("unroll") for (int mf = 0; mf < 4; ++mf) {                       \
        const int row_ = wm * 64 + mf * 16 + r;                                \
        const f16x8 af_ = *(const f16x8*)((buf) + row_ * 64 + kb_);            \
        _Pragma("unroll") for (int nf = 0; nf < 4; ++nf) {                     \
          acc[mf][nf] = __builtin_amdgcn_mfma_f32_16x16x32_f16(                \
              af_, (B)[nf * 2 + kk], acc[mf][nf], 0, 0, 0);                    \
        }                                                                      \
      }                                                                        \
    }                                                                          \
  }
#define BAR()                                          \
  asm volatile("s_waitcnt lgkmcnt(0)" ::: "memory");   \
  __builtin_amdgcn_s_barrier();

#pragma unroll 1
  for (int rep = 0; rep < REP; ++rep) {
    // prologue: buf0 = A(KT0); BE=B(KT0); BO=B(KT1); xA=x(KT1); xB=x(KT2)
    LDX(KT(0), xP);
    LDB(KT(0), BE);
    LDB(KT(1), BO);
    LDX(KT(1), xA);
    LDX(KT(2), xB);
    STW(buf0, xP);
    BAR();

#pragma unroll 1
    for (int it = 0; it < NKT2 / 2; ++it) {
      const int s = it * 2;
      // even step s: compute buf0/BE
      STW(buf1, xA);
      LDX(KT(s + 3), xA);
      COMP(buf0, BE);
      LDB(KT(s + 2), BE);
      BAR();
      // odd step s+1: compute buf1/BO
      STW(buf0, xB);
      LDX(KT(s + 4), xB);
      COMP(buf1, BO);
      LDB(KT(s + 3), BO);
      BAR();
    }
  }

  // store f32 partials scaled by 1/REP (exact: REP is a power of 2)
  const float scl = 1.0f / (float)REP;
  float* hp = hpart + (size_t)ks * HP_SLICE + (size_t)brow * H_DIM;
#pragma unroll
  for (int mf = 0; mf < 4; ++mf)
#pragma unroll
    for (int nf = 0; nf < 4; ++nf) {
      const int col = wc * 64 + nf * 16 + r;
#pragma unroll
      for (int j = 0; j < 4; ++j) {
        const int row = wm * 64 + mf * 16 + g * 4 + j;
        hp[(size_t)row * H_DIM + col] = acc[mf][nf][j] * scl;
      }
    }
}

// ---- reduce partials + bias + relu + gemm2 + sparsemax (32 rows/block) ----
__launch_bounds__(512)
__global__ void reduce_fused_kernel(const float* __restrict__ hpart,
                                    const float* __restrict__ b1,
                                    const f16* __restrict__ w2s,
                                    const float* __restrict__ b2,
                                    float* __restrict__ out) {
  __shared__ __align__(16) char smem[24576];
  f16* h_lds = (f16*)smem;                 // [32][256] f16 swizzled
  float* u_lds = (float*)(smem + 16384);   // [32][64]

  const int t = threadIdx.x;
  const int lane = t & 63;
  const int wn = t >> 6;
  const int g = lane >> 4, r = lane & 15;
  const int brow = blockIdx.x * 32;

  const float* base = hpart + (size_t)brow * H_DIM;
  float4 s[4];
#pragma unroll
  for (int i = 0; i < 4; ++i)
    s[i] = *(const float4*)(base + (size_t)(i * 512 + t) * 4);
#pragma unroll
  for (int c = 1; c < KSPLIT; ++c) {
    const float* cb = base + (size_t)c * HP_SLICE;
#pragma unroll
    for (int i = 0; i < 4; ++i) {
      const float4 v = *(const float4*)(cb + (size_t)(i * 512 + t) * 4);
      s[i].x += v.x; s[i].y += v.y; s[i].z += v.z; s[i].w += v.w;
    }
  }
#pragma unroll
  for (int i = 0; i < 4; ++i) {
    const int f = i * 512 + t;
    const int row = f >> 6;
    const int col = (f & 63) << 2;
    const float4 bv = *(const float4*)(b1 + col);
    f16x4 hv;
    hv[0] = (f16)fmaxf(s[i].x + bv.x, 0.f);
    hv[1] = (f16)fmaxf(s[i].y + bv.y, 0.f);
    hv[2] = (f16)fmaxf(s[i].z + bv.z, 0.f);
    hv[3] = (f16)fmaxf(s[i].w + bv.w, 0.f);
    *(f16x4*)(h_lds + row * 256 + (col ^ ((row & 7) << 3))) = hv;
  }
  __syncthreads();

  // gemm2: u = h @ w2 + b2 (one 16x16 tile per wave)
  const int rh2 = wn & 1;
  const int cg = wn >> 1;
  f32x4 acc2 = {0.f, 0.f, 0.f, 0.f};
  const f16* w2p = w2s + (size_t)(cg * 8) * 512 + lane * 8;
#pragma unroll
  for (int ksi = 0; ksi < 8; ++ksi) {
    const int arow = rh2 * 16 + r;
    const int kb = ksi * 32 + g * 8;
    const f16x8 af = *(const f16x8*)(h_lds + arow * 256 + (kb ^ ((arow & 7) << 3)));
    const f16x8 bf = *(const f16x8*)(w2p + ksi * 512);
    acc2 = __builtin_amdgcn_mfma_f32_16x16x32_f16(af, bf, acc2, 0, 0, 0);
  }
  {
    const int col = cg * 16 + r;
    const float bias = b2[col];
#pragma unroll
    for (int j = 0; j < 4; ++j) {
      const int row = rh2 * 16 + g * 4 + j;
      u_lds[row * 64 + col] = acc2[j] + bias;
    }
  }
  __syncthreads();

  // bisection sparsemax; 16 lanes/row, 4 vals/lane
  const int srow = wn * 4 + (lane >> 4);
  const int scol = (lane & 15) << 2;
  const float4 uv = *(const float4*)(u_lds + srow * 64 + scol);
  float u0 = uv.x, u1 = uv.y, u2 = uv.z, u3 = uv.w;

  float mx = fmaxf(fmaxf(u0, u1), fmaxf(u2, u3));
  float mn = fminf(fminf(u0, u1), fminf(u2, u3));
#pragma unroll
  for (int m = 1; m < 16; m <<= 1) {
    mx = fmaxf(mx, __shfl_xor(mx, m));
    mn = fminf(mn, __shfl_xor(mn, m));
  }
  float lo = mn - 10.0f, hi = mx;
#pragma unroll 1
  for (int it = 0; it < 32; ++it) {
    const float mid = 0.5f * (lo + hi);
    float sm = fmaxf(u0 - mid, 0.f) + fmaxf(u1 - mid, 0.f) +
               fmaxf(u2 - mid, 0.f) + fmaxf(u3 - mid, 0.f);
#pragma unroll
    for (int m = 1; m < 16; m <<= 1) sm += __shfl_xor(sm, m);
    const bool pos = (sm - 1.0f) > 0.0f;
    lo = pos ? mid : lo;
    hi = pos ? hi : mid;
  }
  const float tau = 0.5f * (lo + hi);
  const float p0 = fmaxf(u0 - tau, 0.f);
  const float p1 = fmaxf(u1 - tau, 0.f);
  const float p2 = fmaxf(u2 - tau, 0.f);
  const float p3 = fmaxf(u3 - tau, 0.f);
  float sum = p0 + p1 + p2 + p3;
#pragma unroll
  for (int m = 1; m < 16; m <<= 1) sum += __shfl_xor(sum, m);
  const float inv = 1.0f / (sum + 1e-8f);
  float4 pv;
  pv.x = p0 * inv; pv.y = p1 * inv; pv.z = p2 * inv; pv.w = p3 * inv;
  *(float4*)(out + (size_t)(brow + srow) * E_DIM + scol) = pv;
}

extern "C" void kernel_launch(void* const* d_in, const int* in_sizes, int n_in,
                              void* d_out, int out_size, void* d_ws, size_t ws_size,
                              hipStream_t stream) {
  const float* x  = (const float*)d_in[0];
  const float* w1 = (const float*)d_in[1];
  const float* b1 = (const float*)d_in[2];
  const float* w2 = (const float*)d_in[3];
  const float* b2 = (const float*)d_in[4];
  float* out = (float*)d_out;

  char* wsb = (char*)d_ws;
  f16* w1s = (f16*)wsb;                        // 2 MB
  f16* w2s = (f16*)(wsb + (2u << 20));         // 32 KB
  float* hpart = (float*)(wsb + (4u << 20));   // 4*8192*256 f32 = 32 MB

  pack_kernel<<<520, 256, 0, stream>>>(w1, w1s, w2, w2s);
  // MEASUREMENT ROUND: gemm1 launched twice, each doing REP=2 internal sweeps.
  // dur_us ~= 58.2 + 3*g1  ->  g1 = (dur_us - 58.2)/3. Both dispatches enter
  // rocprof top-5 (each ~2x g1 > 75us fills) with full counters.
  gemm1_splitk_kernel<<<256, 512, 0, stream>>>(x, w1s, hpart);
  gemm1_splitk_kernel<<<256, 512, 0, stream>>>(x, w1s, hpart);
  reduce_fused_kernel<<<256, 512, 0, stream>>>(hpart, b1, w2s, b2, out);
}

// Round 8
// 53.066 us; speedup vs baseline: 3.0535x; 3.0535x over previous
//
#include <hip/hip_runtime.h>
#include <stdint.h>

typedef _Float16 f16;
typedef _Float16 f16x8 __attribute__((ext_vector_type(8)));
typedef float f32x4 __attribute__((ext_vector_type(4)));

#define D_DIM 4096
#define H_DIM 256
#define E_DIM 64
#define BM 128
#define KSPLIT 4
#define NKT2 16                 // K-steps per slice: 1024/64
#define HP_SLICE (8192 * 256)   // f16 elems per hpart slice

// ---- merged pack: w1 [4096][256] -> w1s fragment order; w2 [256][64] -> w2s ----
__global__ void pack_kernel(const float* __restrict__ w1, f16* __restrict__ w1s,
                            const float* __restrict__ w2, f16* __restrict__ w2s) {
  const int b = blockIdx.x;
  const int t = threadIdx.x;
  if (b < 512) {
    const int u = b * 256 + t;
    const int lane = u & 63;
    const int kk = (u >> 6) & 1;
    const int c16 = (u >> 7) & 15;
    const int kt = u >> 11;
    const int g = lane >> 4, r = lane & 15;
    const int k0 = kt * 64 + kk * 32 + g * 8;
    const int col = c16 * 16 + r;
    f16x8 o;
#pragma unroll
    for (int j = 0; j < 8; ++j) o[j] = (f16)w1[(size_t)(k0 + j) * H_DIM + col];
    *(f16x8*)(w1s + (size_t)u * 8) = o;
  } else {
    const int u = (b - 512) * 256 + t;
    const int lane = u & 63;
    const int ks = (u >> 6) & 7;
    const int cg = u >> 9;
    const int g = lane >> 4, r = lane & 15;
    const int k0 = ks * 32 + g * 8;
    const int col = cg * 16 + r;
    f16x8 o;
#pragma unroll
    for (int j = 0; j < 8; ++j) o[j] = (f16)w2[(size_t)(k0 + j) * E_DIM + col];
    *(f16x8*)(w2s + (size_t)u * 8) = o;
  }
}

// ---- GEMM1 split-K, BM=128: x staged via global_load_lds DMA (f32, ring-4 LDS),
//      counted vmcnt + raw s_barrier (one per K-step), B reg-prefetched dist-2 ----
// LDS tile: f32 [128][64], 16B-halfblock swizzle: elem(row,k) at byte
//   row*256 + ((k>>2) ^ (row&15))*16 + (k&3)*4.  DMA dest is linear; the global
//   SOURCE address is pre-swizzled (rule: both-sides-or-neither).
__launch_bounds__(512, 2)
__global__ void gemm1_splitk_kernel(const float* __restrict__ x,
                                    const f16* __restrict__ w1s,
                                    f16* __restrict__ hpart) {
  __shared__ __align__(16) float xbuf[4][BM * 64];   // 4 x 32 KB ring

  const int t = threadIdx.x;
  const int lane = t & 63;
  const int wn = t >> 6;        // 0..7
  const int wm = wn >> 2, wc = wn & 3;
  const int g = lane >> 4, r = lane & 15;
  const int bid = blockIdx.x;
  const int ks = bid & 3;
  const int brow = (bid >> 2) * BM;
  const int kph = (bid * 5) & 15;
#define KT(s) ((kph + (s)) & 15)

  // DMA mapping: linear LDS slot (wn*4+i)*1024B + lane*16B  <->  row = wn*16 + i*4 + (lane>>4),
  // halfblock hb_log = (lane&15) ^ ((i*4 + (lane>>4)) & 15)  -> global cols hb_log*4 .. +3
  const int drow = lane >> 4;
  int hbo[4];
#pragma unroll
  for (int i = 0; i < 4; ++i) hbo[i] = ((lane & 15) ^ ((i * 4 + drow) & 15)) * 4;
  const float* dbase = x + (size_t)(brow + wn * 16 + drow) * D_DIM + ks * 1024;

  const f16* bptr = w1s + (size_t)ks * (16 * 16384) + (size_t)(wc * 8) * 512 + lane * 8;

  f32x4 acc[4][4];
#pragma unroll
  for (int mf = 0; mf < 4; ++mf)
#pragma unroll
    for (int nf = 0; nf < 4; ++nf) acc[mf][nf] = (f32x4){0.f, 0.f, 0.f, 0.f};

  f16x8 BE[8], BO[8];

#define GLDS(bufidx, kt)                                                        \
  {                                                                             \
    _Pragma("unroll") for (int i = 0; i < 4; ++i) {                             \
      const float* gp_ = dbase + (size_t)(i * 4) * D_DIM + (kt) * 64 + hbo[i];  \
      __builtin_amdgcn_global_load_lds(                                         \
          (const __attribute__((address_space(1))) void*)gp_,                   \
          (__attribute__((address_space(3))) void*)&xbuf[bufidx][(wn * 4 + i) * 256], \
          16, 0, 0);                                                            \
    }                                                                           \
  }
#define LDB(kt, B)                                                      \
  {                                                                     \
    const f16* p_ = bptr + (size_t)(kt) * 16384;                        \
    _Pragma("unroll") for (int q = 0; q < 8; ++q)                       \
      (B)[q] = *(const f16x8*)(p_ + q * 512);                           \
  }
  // A-fragment: row = wm*64+mf*16+r (row&15 == r), k-halfblocks L0=kk*8+g*2, L0+1
#define COMP(bufidx, B)                                                         \
  {                                                                             \
    _Pragma("unroll") for (int kk = 0; kk < 2; ++kk) {                          \
      _Pragma("unroll") for (int mf = 0; mf < 4; ++mf) {                        \
        const int row_ = wm * 64 + mf * 16 + r;                                 \
        const float* bp_ = &xbuf[bufidx][row_ * 64];                            \
        const int L0_ = kk * 8 + g * 2;                                         \
        const float4 a0_ = *(const float4*)(bp_ + ((L0_ ^ r) << 2));            \
        const float4 a1_ = *(const float4*)(bp_ + (((L0_ + 1) ^ r) << 2));      \
        f16x8 af_;                                                              \
        af_[0] = (f16)a0_.x; af_[1] = (f16)a0_.y;                               \
        af_[2] = (f16)a0_.z; af_[3] = (f16)a0_.w;                               \
        af_[4] = (f16)a1_.x; af_[5] = (f16)a1_.y;                               \
        af_[6] = (f16)a1_.z; af_[7] = (f16)a1_.w;                               \
        _Pragma("unroll") for (int nf = 0; nf < 4; ++nf)                        \
          acc[mf][nf] = __builtin_amdgcn_mfma_f32_16x16x32_f16(                 \
              af_, (B)[nf * 2 + kk], acc[mf][nf], 0, 0, 0);                     \
      }                                                                         \
    }                                                                           \
  }
  // full step: prefetch dist-2; vmcnt(16) = allow {GLDS(s+1),LDB(s+1),GLDS(s+2)} in flight,
  // which retires GLDS(s)+LDB(s). Own-drain-then-barrier => all waves' DMAs landed.
#define STEP(s, bidx, B)                                  \
  {                                                       \
    GLDS(((s) + 2) & 3, KT((s) + 2));                     \
    asm volatile("s_waitcnt vmcnt(16)" ::: "memory");     \
    __builtin_amdgcn_s_barrier();                         \
    COMP(bidx, B);                                        \
    LDB(KT((s) + 2), B);                                  \
  }
#define STEPN(s, bidx, B, WAIT)                           \
  {                                                       \
    asm volatile(WAIT ::: "memory");                      \
    __builtin_amdgcn_s_barrier();                         \
    COMP(bidx, B);                                        \
  }

  // prologue: batches {GLDS(0),LDB(0)}, {GLDS(1),LDB(1)}
  GLDS(0, KT(0));
  LDB(KT(0), BE);
  GLDS(1, KT(1));
  LDB(KT(1), BO);

#pragma unroll 1
  for (int q = 0; q < 3; ++q) {
    const int s0 = q * 4;
    STEP(s0 + 0, 0, BE);
    STEP(s0 + 1, 1, BO);
    STEP(s0 + 2, 2, BE);
    STEP(s0 + 3, 3, BO);
  }
  STEP(12, 0, BE);
  STEP(13, 1, BO);
  STEPN(14, 2, BE, "s_waitcnt vmcnt(12)");   // batch(15) may stay in flight
  STEPN(15, 3, BO, "s_waitcnt vmcnt(0)");    // drain batch(15)

  // epilogue: store f16 partials hpart[ks][brow+row][col]
  f16* hp = hpart + (size_t)ks * HP_SLICE + (size_t)brow * H_DIM;
#pragma unroll
  for (int mf = 0; mf < 4; ++mf)
#pragma unroll
    for (int nf = 0; nf < 4; ++nf) {
      const int col = wc * 64 + nf * 16 + r;
#pragma unroll
      for (int j = 0; j < 4; ++j) {
        const int row = wm * 64 + mf * 16 + g * 4 + j;
        hp[(size_t)row * H_DIM + col] = (f16)acc[mf][nf][j];
      }
    }
}

// ---- reduce f16 partials + bias + relu + gemm2 + sparsemax (32 rows/block) ----
__launch_bounds__(512)
__global__ void reduce_fused_kernel(const f16* __restrict__ hpart,
                                    const float* __restrict__ b1,
                                    const f16* __restrict__ w2s,
                                    const float* __restrict__ b2,
                                    float* __restrict__ out) {
  __shared__ __align__(16) char smem[24576];
  f16* h_lds = (f16*)smem;                 // [32][256] f16, 8-granule XOR swizzle
  float* u_lds = (float*)(smem + 16384);   // [32][64]

  const int t = threadIdx.x;
  const int lane = t & 63;
  const int wn = t >> 6;
  const int g = lane >> 4, r = lane & 15;
  const int brow = blockIdx.x * 32;

  const int row = t >> 4;            // 0..31
  const int col0 = (t & 15) << 4;    // 0..240
  const f16* base = hpart + (size_t)(brow + row) * H_DIM + col0;
  float a[16];
#pragma unroll
  for (int j = 0; j < 16; ++j) a[j] = 0.f;
#pragma unroll
  for (int c = 0; c < KSPLIT; ++c) {
    const f16x8 va = *(const f16x8*)(base + (size_t)c * HP_SLICE);
    const f16x8 vb = *(const f16x8*)(base + (size_t)c * HP_SLICE + 8);
#pragma unroll
    for (int j = 0; j < 8; ++j) { a[j] += (float)va[j]; a[8 + j] += (float)vb[j]; }
  }
  {
    const int s8 = (row & 7) << 3;
    f16x8 h0, h1;
#pragma unroll
    for (int j = 0; j < 8; ++j) {
      h0[j] = (f16)fmaxf(a[j] + b1[col0 + j], 0.f);
      h1[j] = (f16)fmaxf(a[8 + j] + b1[col0 + 8 + j], 0.f);
    }
    *(f16x8*)(h_lds + row * 256 + (col0 ^ s8)) = h0;
    *(f16x8*)(h_lds + row * 256 + ((col0 + 8) ^ s8)) = h1;
  }
  __syncthreads();

  // gemm2: u = h @ w2 + b2 (one 16x16 tile per wave)
  const int rh2 = wn & 1;
  const int cg = wn >> 1;
  f32x4 acc2 = {0.f, 0.f, 0.f, 0.f};
  const f16* w2p = w2s + (size_t)(cg * 8) * 512 + lane * 8;
#pragma unroll
  for (int ksi = 0; ksi < 8; ++ksi) {
    const int arow = rh2 * 16 + r;
    const int kb = ksi * 32 + g * 8;
    const f16x8 af = *(const f16x8*)(h_lds + arow * 256 + (kb ^ ((arow & 7) << 3)));
    const f16x8 bf = *(const f16x8*)(w2p + ksi * 512);
    acc2 = __builtin_amdgcn_mfma_f32_16x16x32_f16(af, bf, acc2, 0, 0, 0);
  }
  {
    const int col = cg * 16 + r;
    const float bias = b2[col];
#pragma unroll
    for (int j = 0; j < 4; ++j) {
      const int rr = rh2 * 16 + g * 4 + j;
      u_lds[rr * 64 + col] = acc2[j] + bias;
    }
  }
  __syncthreads();

  // bisection sparsemax; 16 lanes/row, 4 vals/lane
  const int srow = wn * 4 + (lane >> 4);
  const int scol = (lane & 15) << 2;
  const float4 uv = *(const float4*)(u_lds + srow * 64 + scol);
  float u0 = uv.x, u1 = uv.y, u2 = uv.z, u3 = uv.w;

  float mx = fmaxf(fmaxf(u0, u1), fmaxf(u2, u3));
  float mn = fminf(fminf(u0, u1), fminf(u2, u3));
#pragma unroll
  for (int m = 1; m < 16; m <<= 1) {
    mx = fmaxf(mx, __shfl_xor(mx, m));
    mn = fminf(mn, __shfl_xor(mn, m));
  }
  float lo = mn - 10.0f, hi = mx;
#pragma unroll 1
  for (int it = 0; it < 32; ++it) {
    const float mid = 0.5f * (lo + hi);
    float sm = fmaxf(u0 - mid, 0.f) + fmaxf(u1 - mid, 0.f) +
               fmaxf(u2 - mid, 0.f) + fmaxf(u3 - mid, 0.f);
#pragma unroll
    for (int m = 1; m < 16; m <<= 1) sm += __shfl_xor(sm, m);
    const bool pos = (sm - 1.0f) > 0.0f;
    lo = pos ? mid : lo;
    hi = pos ? hi : mid;
  }
  const float tau = 0.5f * (lo + hi);
  const float p0 = fmaxf(u0 - tau, 0.f);
  const float p1 = fmaxf(u1 - tau, 0.f);
  const float p2 = fmaxf(u2 - tau, 0.f);
  const float p3 = fmaxf(u3 - tau, 0.f);
  float sum = p0 + p1 + p2 + p3;
#pragma unroll
  for (int m = 1; m < 16; m <<= 1) sum += __shfl_xor(sum, m);
  const float inv = 1.0f / (sum + 1e-8f);
  float4 pv;
  pv.x = p0 * inv; pv.y = p1 * inv; pv.z = p2 * inv; pv.w = p3 * inv;
  *(float4*)(out + (size_t)(brow + srow) * E_DIM + scol) = pv;
}

extern "C" void kernel_launch(void* const* d_in, const int* in_sizes, int n_in,
                              void* d_out, int out_size, void* d_ws, size_t ws_size,
                              hipStream_t stream) {
  const float* x  = (const float*)d_in[0];
  const float* w1 = (const float*)d_in[1];
  const float* b1 = (const float*)d_in[2];
  const float* w2 = (const float*)d_in[3];
  const float* b2 = (const float*)d_in[4];
  float* out = (float*)d_out;

  char* wsb = (char*)d_ws;
  f16* w1s = (f16*)wsb;                      // 2 MB
  f16* w2s = (f16*)(wsb + (2u << 20));       // 32 KB
  f16* hpart = (f16*)(wsb + (4u << 20));     // 4*8192*256 f16 = 16 MB

  pack_kernel<<<520, 256, 0, stream>>>(w1, w1s, w2, w2s);
  gemm1_splitk_kernel<<<256, 512, 0, stream>>>(x, w1s, hpart);
  reduce_fused_kernel<<<256, 512, 0, stream>>>(hpart, b1, w2s, b2, out);
}